// Round 6
// baseline (201.541 us; speedup 1.0000x reference)
//
#include <hip/hip_runtime.h>
#include <math.h>

#define BB 4
#define NN 2048
#define MM 128
#define DD 64
#define NEG_SLOPE 0.2f

#define NSB 16                // n splits
#define MTB 4                 // m tiles
#define MW  32                // m per block
#define NR  128               // n per block (NN/NSB)

// ---------------------------------------------------------------------------
// K1: per (ns, mt, b) block, fully self-contained:
//   phase0: stage fs chunk -> LDS; load W_src row into regs; u_r, c_e
//   phase1: hs = fs @ W_src^T in-place in LDS; el via wave reduce; er
//   phase2: masked-leaky scores, p = exp(s) (no max pass; scores bounded)
//   phase3: partial aggregation acc[m][d] = sum_n p*hs -> pacc, denom/sfe -> pdn
// No global intermediates besides pacc/pdn; no inter-block dependencies.
// ---------------------------------------------------------------------------
__global__ __launch_bounds__(256) void fused_all_kernel(
        const float* __restrict__ fs, const float* __restrict__ W_src,
        const float* __restrict__ attn_l,
        const float* __restrict__ fd, const float* __restrict__ W_dst,
        const float* __restrict__ attn_r,
        const float* __restrict__ W_edge, const float* __restrict__ attn_e,
        const float* __restrict__ fe, const int* __restrict__ adj,
        float* __restrict__ pacc, float* __restrict__ pdn) {
    int bid = blockIdx.x;
    int ns = bid & 15, mt = (bid >> 4) & 3, b = bid >> 6;
    int n0 = ns * NR, m0 = mt * MW;
    int t = threadIdx.x, lane = t & 63, g = t >> 6;

    __shared__ __align__(16) float fsh[NR * DD];      // 32 KB: fs, then hs
    __shared__ __align__(16) float p_lds[MW * (NR + 4)]; // 16.9 KB
    __shared__ float el_lds[NR];
    __shared__ float er_lds[MW];
    __shared__ float dred[8 * (MW + 1)];
    __shared__ float fred[8 * (MW + 1)];
    __shared__ __align__(16) float u_r[DD];
    __shared__ float ce_s;

    // ---- phase 0 ----
    const float4* fs4 = (const float4*)(fs + ((size_t)(b * NN + n0)) * DD);
#pragma unroll
    for (int k = 0; k < 8; ++k)
        ((float4*)fsh)[t + k * 256] = fs4[t + k * 256];

    float4 wreg[16];
    const float4* w4 = (const float4*)(W_src + (size_t)lane * DD);
#pragma unroll
    for (int k = 0; k < 16; ++k) wreg[k] = w4[k];
    float al = attn_l[lane];

    if (t < 64) {                       // u_r[t] = sum_d attn_r[d]*W_dst[d,t]
        float a = 0.f;
#pragma unroll 8
        for (int dd = 0; dd < DD; ++dd) a += attn_r[dd] * W_dst[dd * DD + t];
        u_r[t] = a;
    } else if (t < 128) {               // c_e = W_edge . attn_e (wave 1)
        float v = W_edge[lane] * attn_e[lane];
#pragma unroll
        for (int off = 32; off > 0; off >>= 1) v += __shfl_xor(v, off, 64);
        if (lane == 0) ce_s = v;
    }
    __syncthreads();

    // ---- phase 1: hs (in-place), el, er ----
    if (t < MW) {                       // er for this block's 32 m's
        float a2 = 0.f;
        const float4* fd4 = (const float4*)(fd + (size_t)(b * MM + m0 + t) * DD);
        const float4* ur4 = (const float4*)u_r;
#pragma unroll
        for (int k = 0; k < 16; ++k) {
            float4 f = fd4[k], u = ur4[k];
            a2 += f.x * u.x + f.y * u.y + f.z * u.z + f.w * u.w;
        }
        er_lds[t] = a2;
    }
#pragma unroll
    for (int bt = 0; bt < 2; ++bt) {    // wave g owns rows g*32..g*32+31
        int r0 = g * 32 + bt * 16;
        float acc[16];
#pragma unroll
        for (int rr = 0; rr < 16; ++rr) acc[rr] = 0.f;
#pragma unroll
        for (int k4 = 0; k4 < 16; ++k4) {
            float4 wk = wreg[k4];
#pragma unroll
            for (int rr = 0; rr < 16; ++rr) {
                float4 rv = ((const float4*)fsh)[(r0 + rr) * 16 + k4]; // bcast
                acc[rr] += rv.x * wk.x + rv.y * wk.y + rv.z * wk.z + rv.w * wk.w;
            }
        }
#pragma unroll
        for (int rr = 0; rr < 16; ++rr) {        // el via wave reduce
            float e = acc[rr] * al;
#pragma unroll
            for (int off = 32; off > 0; off >>= 1) e += __shfl_xor(e, off, 64);
            if (lane == 0) el_lds[r0 + rr] = e;
        }
#pragma unroll
        for (int rr = 0; rr < 16; ++rr)          // overwrite fs row with hs
            fsh[(r0 + rr) * DD + lane] = acc[rr];
    }
    __syncthreads();

    // ---- phase 2: scores ----
    {
        int m = t & 31, h = t >> 5;              // 32 m-lanes coalesced
        float ce = ce_s;
        float er_m = er_lds[m];
        const float* fe_p = fe + ((size_t)(b * NN + n0)) * MM + m0 + m;
        const int* adj_p = adj + ((size_t)(b * NN + n0)) * MM + m0 + m;
        float dsum = 0.f, fsum = 0.f;
#pragma unroll
        for (int j = 0; j < 16; ++j) {
            int n = h + j * 8;
            float f = fe_p[(size_t)n * MM];
            int a = adj_p[(size_t)n * MM];
            float s = el_lds[n] + ce * f + er_m;
            s = s > 0.f ? s : NEG_SLOPE * s;
            float p = (a == 1) ? __expf(s) : 0.f;
            p_lds[m * (NR + 4) + n] = p;
            dsum += p;
            fsum += f * p;
        }
        dred[h * (MW + 1) + m] = dsum;
        fred[h * (MW + 1) + m] = fsum;
    }
    __syncthreads();

    // ---- phase 3: aggregation ----
    size_t pbase = (size_t)((b * MTB + mt) * NSB + ns) * MW;
    {
        int d = lane;
        float acc8[8];
#pragma unroll
        for (int jj = 0; jj < 8; ++jj) acc8[jj] = 0.f;
        for (int n4 = 0; n4 < NR / 4; ++n4) {
            float h0 = fsh[(n4 * 4 + 0) * DD + d];
            float h1 = fsh[(n4 * 4 + 1) * DD + d];
            float h2 = fsh[(n4 * 4 + 2) * DD + d];
            float h3 = fsh[(n4 * 4 + 3) * DD + d];
#pragma unroll
            for (int jj = 0; jj < 8; ++jj) {
                float4 p = *(const float4*)&p_lds[(g * 8 + jj) * (NR + 4) + n4 * 4];
                acc8[jj] += p.x * h0 + p.y * h1 + p.z * h2 + p.w * h3;
            }
        }
#pragma unroll
        for (int jj = 0; jj < 8; ++jj)
            pacc[(pbase + g * 8 + jj) * DD + d] = acc8[jj];
    }
    if (t < MW) {
        float ds = 0.f, fs2 = 0.f;
#pragma unroll
        for (int h = 0; h < 8; ++h) {
            ds  += dred[h * (MW + 1) + t];
            fs2 += fred[h * (MW + 1) + t];
        }
        size_t q = (pbase + t) * 2;
        pdn[q] = ds;
        pdn[q + 1] = fs2;
    }
}

// ---------------------------------------------------------------------------
// K2: out[bm,d] = sigmoid((W_edge[d]*Σsfe + Σacc) / Σdenom)  over ns
// ---------------------------------------------------------------------------
__global__ __launch_bounds__(256) void reduce_kernel(
        const float* __restrict__ pacc, const float* __restrict__ pdn,
        const float* __restrict__ W_edge, float* __restrict__ out) {
    int gid = blockIdx.x * 256 + threadIdx.x;   // 32768
    int d = gid & 63, bm = gid >> 6;
    int b = bm >> 7, mmv = bm & 127;
    int mt = mmv >> 5, ml = mmv & 31;
    size_t base = ((size_t)(b * MTB + mt)) * NSB;
    float accs = 0.f, dens = 0.f, sfes = 0.f;
#pragma unroll
    for (int ns = 0; ns < NSB; ++ns) {
        size_t idx = (base + ns) * MW + ml;
        accs += pacc[idx * DD + d];
        dens += pdn[idx * 2];
        sfes += pdn[idx * 2 + 1];
    }
    float v = (W_edge[d] * sfes + accs) / dens;
    out[(size_t)bm * DD + d] = 1.f / (1.f + __expf(-v));
}

extern "C" void kernel_launch(void* const* d_in, const int* in_sizes, int n_in,
                              void* d_out, int out_size, void* d_ws, size_t ws_size,
                              hipStream_t stream) {
    const float* feat_src  = (const float*)d_in[0];
    const float* feat_dst  = (const float*)d_in[1];
    const float* feat_edge = (const float*)d_in[2];
    const int*   adj       = (const int*)d_in[3];
    const float* W_src     = (const float*)d_in[4];
    const float* W_dst     = (const float*)d_in[5];
    const float* W_edge    = (const float*)d_in[6];
    const float* attn_l    = (const float*)d_in[7];
    const float* attn_r    = (const float*)d_in[8];
    const float* attn_e    = (const float*)d_in[9];
    float* out = (float*)d_out;

    float* ws   = (float*)d_ws;
    float* pacc = ws;                                  // 4*4*16*32*64 = 524288
    float* pdn  = pacc + (size_t)BB * MTB * NSB * MW * DD;  // 16384

    fused_all_kernel<<<256, 256, 0, stream>>>(
        feat_src, W_src, attn_l, feat_dst, W_dst, attn_r,
        W_edge, attn_e, feat_edge, adj, pacc, pdn);
    reduce_kernel<<<128, 256, 0, stream>>>(pacc, pdn, W_edge, out);
}

// Round 7
// 37.327 us; speedup vs baseline: 5.3993x; 5.3993x over previous
//
#include <hip/hip_runtime.h>
#include <math.h>

#define BB 4
#define NN 2048
#define MM 128
#define DD 64
#define NEG_SLOPE 0.2f

#define CH  32                // n per block
#define NCH (NN / CH)         // 64 chunks
#define PSTR (MM + 4)         // p_lds row stride (132; 132*4B=528B, 16B-aligned)

// ---------------------------------------------------------------------------
// K1: per (ch, b) block, fully self-contained:
//   phase0: stage fs chunk -> LDS; W_src row -> 64 VGPR; u_r; c_e
//   phase1: hs = fs @ W_src^T in place (acc[4] batches); el; er (all 128 m)
//   phase2: scores p=exp(masked leaky) — fe/adj reads are full 512B lines
//   phase3: agg acc[16m][2d] over 32 n -> pacc; denom/sfe -> pdn
// ---------------------------------------------------------------------------
__global__ __launch_bounds__(256, 2) void fused_all_kernel(
        const float* __restrict__ fs, const float* __restrict__ W_src,
        const float* __restrict__ attn_l,
        const float* __restrict__ fd, const float* __restrict__ W_dst,
        const float* __restrict__ attn_r,
        const float* __restrict__ W_edge, const float* __restrict__ attn_e,
        const float* __restrict__ fe, const int* __restrict__ adj,
        float* __restrict__ pacc, float* __restrict__ pdn) {
    int ch = blockIdx.x, b = blockIdx.y;
    int n0 = ch * CH;
    int t = threadIdx.x, lane = t & 63, g = t >> 6;

    __shared__ __align__(16) float fsh[CH * DD];       // 8 KB: fs then hs
    __shared__ __align__(16) float p_lds[CH * PSTR];   // 16.5 KB
    __shared__ float el_lds[CH];
    __shared__ float er_lds[MM];
    __shared__ __align__(16) float u_r[DD];
    __shared__ float dred[2][MM], fred[2][MM];
    __shared__ float ce_s;

    // ---- phase 0 ----
    const float4* fs4 = (const float4*)(fs + ((size_t)(b * NN + n0)) * DD);
    ((float4*)fsh)[t] = fs4[t];
    ((float4*)fsh)[t + 256] = fs4[t + 256];

    float4 wreg[16];
    const float4* w4 = (const float4*)(W_src + (size_t)lane * DD);
#pragma unroll
    for (int k = 0; k < 16; ++k) wreg[k] = w4[k];
    float al = attn_l[lane];

    if (t < 64) {                        // u_r[t] = sum_d attn_r[d]*W_dst[d,t]
        float a = 0.f;
#pragma unroll 8
        for (int dd = 0; dd < DD; ++dd) a += attn_r[dd] * W_dst[dd * DD + t];
        u_r[t] = a;
    } else if (t < 128) {                // c_e (wave 1)
        float v = W_edge[lane] * attn_e[lane];
#pragma unroll
        for (int off = 32; off > 0; off >>= 1) v += __shfl_xor(v, off, 64);
        if (lane == 0) ce_s = v;
    }
    __syncthreads();

    // ---- phase 1: er + proj (8 rows/wave in 2 batches of 4) ----
    if (t < MM) {
        float a2 = 0.f;
        const float4* fd4 = (const float4*)(fd + (size_t)(b * MM + t) * DD);
        const float4* ur4 = (const float4*)u_r;
#pragma unroll
        for (int k = 0; k < 16; ++k) {
            float4 f = fd4[k], u = ur4[k];
            a2 += f.x * u.x + f.y * u.y + f.z * u.z + f.w * u.w;
        }
        er_lds[t] = a2;
    }
#pragma unroll
    for (int it2 = 0; it2 < 2; ++it2) {
        int r0 = g * 8 + it2 * 4;
        float acc[4] = {0.f, 0.f, 0.f, 0.f};
#pragma unroll 4
        for (int k4 = 0; k4 < 16; ++k4) {
            float4 wk = wreg[k4];
#pragma unroll
            for (int rr = 0; rr < 4; ++rr) {
                float4 rv = ((const float4*)fsh)[(r0 + rr) * 16 + k4]; // bcast
                acc[rr] += rv.x * wk.x + rv.y * wk.y + rv.z * wk.z + rv.w * wk.w;
            }
        }
#pragma unroll
        for (int rr = 0; rr < 4; ++rr) {
            float e = acc[rr] * al;
#pragma unroll
            for (int off = 32; off > 0; off >>= 1) e += __shfl_xor(e, off, 64);
            if (lane == 0) el_lds[r0 + rr] = e;
        }
#pragma unroll
        for (int rr = 0; rr < 4; ++rr)     // rows fully consumed; overwrite
            fsh[(r0 + rr) * DD + lane] = acc[rr];
    }
    __syncthreads();

    // ---- phase 2: scores, fully coalesced fe/adj ----
    {
        int m = t & 127, h = t >> 7;
        float ce = ce_s;
        float er_m = er_lds[m];
        const float* fe_p = fe + ((size_t)(b * NN + n0)) * MM + m;
        const int* adj_p = adj + ((size_t)(b * NN + n0)) * MM + m;
        float dsum = 0.f, fsum = 0.f;
#pragma unroll 4
        for (int j = 0; j < 16; ++j) {
            int n = h * 16 + j;
            float f = fe_p[(size_t)n * MM];
            int a = adj_p[(size_t)n * MM];
            float s = el_lds[n] + ce * f + er_m;
            s = s > 0.f ? s : NEG_SLOPE * s;
            float p = (a == 1) ? __expf(s) : 0.f;
            p_lds[n * PSTR + m] = p;
            dsum += p;
            fsum += f * p;
        }
        dred[h][m] = dsum;
        fred[h][m] = fsum;
    }
    __syncthreads();

    // ---- phase 3: aggregation; thread owns m=mq*16+{0..15}, d=dq*2+{0,1} ----
    {
        int mq = t >> 5, dq = t & 31;
        float a0[16], a1[16];
#pragma unroll
        for (int i = 0; i < 16; ++i) { a0[i] = 0.f; a1[i] = 0.f; }
#pragma unroll 4
        for (int n = 0; n < CH; ++n) {
            float2 hv = *(const float2*)&fsh[n * DD + dq * 2];
#pragma unroll
            for (int q = 0; q < 4; ++q) {
                float4 p4 = *(const float4*)&p_lds[n * PSTR + mq * 16 + q * 4];
                a0[q * 4 + 0] += p4.x * hv.x; a1[q * 4 + 0] += p4.x * hv.y;
                a0[q * 4 + 1] += p4.y * hv.x; a1[q * 4 + 1] += p4.y * hv.y;
                a0[q * 4 + 2] += p4.z * hv.x; a1[q * 4 + 2] += p4.z * hv.y;
                a0[q * 4 + 3] += p4.w * hv.x; a1[q * 4 + 3] += p4.w * hv.y;
            }
        }
        size_t obase = (size_t)(b * NCH + ch) * MM;
#pragma unroll
        for (int mm = 0; mm < 16; ++mm) {
            int m2 = mq * 16 + mm;
            *(float2*)&pacc[(obase + m2) * DD + dq * 2] =
                make_float2(a0[mm], a1[mm]);
        }
        if (t < MM) {
            float dn = dred[0][t] + dred[1][t];
            float sf = fred[0][t] + fred[1][t];
            size_t q2 = (obase + t) * 2;
            pdn[q2] = dn;
            pdn[q2 + 1] = sf;
        }
    }
}

// ---------------------------------------------------------------------------
// K2: out[bm,d] = sigmoid((W_edge[d]*Σsfe + Σacc) / Σdenom) over 64 chunks
// ---------------------------------------------------------------------------
__global__ __launch_bounds__(256) void reduce_kernel(
        const float* __restrict__ pacc, const float* __restrict__ pdn,
        const float* __restrict__ W_edge, float* __restrict__ out) {
    int gid = blockIdx.x * 256 + threadIdx.x;   // 32768
    int d = gid & 63, bm = gid >> 6;
    int b = bm >> 7, m = bm & 127;
    float accs = 0.f, dens = 0.f, sfes = 0.f;
#pragma unroll 8
    for (int ch = 0; ch < NCH; ++ch) {
        size_t idx = (size_t)(b * NCH + ch) * MM + m;
        accs += pacc[idx * DD + d];
        dens += pdn[idx * 2];
        sfes += pdn[idx * 2 + 1];
    }
    float v = (W_edge[d] * sfes + accs) / dens;
    out[(size_t)bm * DD + d] = 1.f / (1.f + __expf(-v));
}

extern "C" void kernel_launch(void* const* d_in, const int* in_sizes, int n_in,
                              void* d_out, int out_size, void* d_ws, size_t ws_size,
                              hipStream_t stream) {
    const float* feat_src  = (const float*)d_in[0];
    const float* feat_dst  = (const float*)d_in[1];
    const float* feat_edge = (const float*)d_in[2];
    const int*   adj       = (const int*)d_in[3];
    const float* W_src     = (const float*)d_in[4];
    const float* W_dst     = (const float*)d_in[5];
    const float* W_edge    = (const float*)d_in[6];
    const float* attn_l    = (const float*)d_in[7];
    const float* attn_r    = (const float*)d_in[8];
    const float* attn_e    = (const float*)d_in[9];
    float* out = (float*)d_out;

    float* ws   = (float*)d_ws;
    float* pacc = ws;                                   // 4*64*128*64 = 2097152
    float* pdn  = pacc + (size_t)BB * NCH * MM * DD;    // 65536

    fused_all_kernel<<<dim3(NCH, BB), 256, 0, stream>>>(
        feat_src, W_src, attn_l, feat_dst, W_dst, attn_r,
        W_edge, attn_e, feat_edge, adj, pacc, pdn);
    reduce_kernel<<<128, 256, 0, stream>>>(pacc, pdn, W_edge, out);
}